// Round 2
// 1736.578 us; speedup vs baseline: 1.0994x; 1.0994x over previous
//
#include <hip/hip_runtime.h>
#include <math.h>

// ---------------------------------------------------------------------------
// Shapes: T=128, N=32 -> TN=4096
//  x: (4096,4,64,64) f32 | conv1 (32,4,8,8)s4 -> a1 (4096,32,15,15)
//  conv2 (64,32,4,4)s2 -> a2 (4096,64,6,6) | conv3 (64,64,3,3)s1 -> a3 (4096,1024)
//  fc (512,1024) -> feats (4096,512) | lstm wi(1024,512) wh(1024,256) H=256
//  heads: actor(18,256) critic(1,256) -> out (4096,19)
// ---------------------------------------------------------------------------

typedef _Float16 half2_t __attribute__((ext_vector_type(2)));

__device__ inline float dot8(float4 a, float4 b, float4 wa, float4 wb, float s) {
  s = fmaf(a.x, wa.x, s); s = fmaf(a.y, wa.y, s);
  s = fmaf(a.z, wa.z, s); s = fmaf(a.w, wa.w, s);
  s = fmaf(b.x, wb.x, s); s = fmaf(b.y, wb.y, s);
  s = fmaf(b.z, wb.z, s); s = fmaf(b.w, wb.w, s);
  return s;
}

// ---- conv1 v3: block = frame; x staged one channel at a time into LDS ----
__global__ __launch_bounds__(256) void conv1_kernel(
    const float* __restrict__ x, const float* __restrict__ w,
    const float* __restrict__ bias, float* __restrict__ out) {
  __shared__ float xs[64 * 68];      // 17408 B, one input channel
  const int n = blockIdx.x;
  const int t = threadIdx.x;
  const int oy = t >> 4;             // 0..15 (15 idle in compute)
  const int og = t & 15;
  const int oc0 = og * 2;

  float acc[15][2] = {};
  const float4* xg = (const float4*)(x + (size_t)n * 16384);
  const float* wb = w + oc0 * 256;   // oc stride 4*8*8=256

  for (int c = 0; c < 4; ++c) {
    __syncthreads();                 // previous channel consumed
    #pragma unroll
    for (int i = 0; i < 4; ++i) {    // stage 1024 float4
      int f4 = i * 256 + t;
      int y = f4 >> 4, xq = f4 & 15;
      *(float4*)&xs[y * 68 + xq * 4] = xg[c * 1024 + f4];
    }
    __syncthreads();
    if (oy < 15) {
      for (int ky = 0; ky < 8; ++ky) {
        const float* xr = &xs[(4 * oy + ky) * 68];
        const float* wr = wb + c * 64 + ky * 8;
        const float4 w00 = *(const float4*)(wr);
        const float4 w01 = *(const float4*)(wr + 4);
        const float4 w10 = *(const float4*)(wr + 256);
        const float4 w11 = *(const float4*)(wr + 260);
        {
          float4 xv[9];
          #pragma unroll
          for (int i = 0; i < 9; ++i) xv[i] = *(const float4*)(xr + 4 * i);
          #pragma unroll
          for (int p = 0; p < 8; ++p) {
            acc[p][0] = dot8(xv[p], xv[p + 1], w00, w01, acc[p][0]);
            acc[p][1] = dot8(xv[p], xv[p + 1], w10, w11, acc[p][1]);
          }
        }
        {
          float4 yv[8];
          #pragma unroll
          for (int i = 0; i < 8; ++i) yv[i] = *(const float4*)(xr + 32 + 4 * i);
          #pragma unroll
          for (int p = 8; p < 15; ++p) {
            acc[p][0] = dot8(yv[p - 8], yv[p - 7], w00, w01, acc[p][0]);
            acc[p][1] = dot8(yv[p - 8], yv[p - 7], w10, w11, acc[p][1]);
          }
        }
      }
    }
  }
  if (oy < 15) {
    const float inv = 1.f / 255.f;
    #pragma unroll
    for (int o = 0; o < 2; ++o) {
      const int oc = oc0 + o;
      const float bb = bias[oc];
      float* orow = out + ((size_t)n * 32 + oc) * 225 + oy * 15;
      #pragma unroll
      for (int p = 0; p < 15; ++p)
        orow[p] = fmaxf(fmaf(acc[p][o], inv, bb), 0.f);
    }
  }
}

// ---- conv2 v3: block = frame (192 thr); a1 frame staged in LDS ----
__global__ __launch_bounds__(192) void conv2_kernel(
    const float* __restrict__ a1, const float* __restrict__ w,
    const float* __restrict__ bias, float* __restrict__ out) {
  __shared__ float xs[32 * 15 * 16];   // 30720 B
  const int n = blockIdx.x;
  const int t = threadIdx.x;           // 0..191
  const float* ag = a1 + (size_t)n * 7200;
  for (int i = 0; i < 38; ++i) {
    int idx = i * 192 + t;
    if (idx < 7200) {
      int c = idx / 225, rem = idx - c * 225;
      int row = rem / 15, col = rem - row * 15;
      xs[(c * 15 + row) * 16 + col] = ag[idx];
    }
  }
  __syncthreads();

  const int oy = t >> 5;               // 0..5
  const int op = t & 31;
  const int oc0 = op * 2;
  float acc[6][2] = {};
  const float* wb = w + oc0 * 512;     // oc stride 32*4*4=512

  for (int c = 0; c < 32; ++c) {
    #pragma unroll
    for (int ky = 0; ky < 4; ++ky) {
      const float* xr = &xs[(c * 15 + 2 * oy + ky) * 16];
      const float4 xa = *(const float4*)(xr);
      const float4 xb = *(const float4*)(xr + 4);
      const float4 xc = *(const float4*)(xr + 8);
      const float2 xd = *(const float2*)(xr + 12);
      const float xv[14] = {xa.x, xa.y, xa.z, xa.w, xb.x, xb.y, xb.z, xb.w,
                            xc.x, xc.y, xc.z, xc.w, xd.x, xd.y};
      const float* wr = wb + c * 16 + ky * 4;
      const float4 w0 = *(const float4*)(wr);
      const float4 w1 = *(const float4*)(wr + 512);
      #pragma unroll
      for (int p = 0; p < 6; ++p) {
        const int b = 2 * p;
        float s0 = acc[p][0], s1 = acc[p][1];
        s0 = fmaf(xv[b], w0.x, s0);     s1 = fmaf(xv[b], w1.x, s1);
        s0 = fmaf(xv[b + 1], w0.y, s0); s1 = fmaf(xv[b + 1], w1.y, s1);
        s0 = fmaf(xv[b + 2], w0.z, s0); s1 = fmaf(xv[b + 2], w1.z, s1);
        s0 = fmaf(xv[b + 3], w0.w, s0); s1 = fmaf(xv[b + 3], w1.w, s1);
        acc[p][0] = s0; acc[p][1] = s1;
      }
    }
  }
  #pragma unroll
  for (int o = 0; o < 2; ++o) {
    const int oc = oc0 + o;
    const float bb = bias[oc];
    float* orow = out + ((size_t)n * 64 + oc) * 36 + oy * 6;
    #pragma unroll
    for (int p = 0; p < 6; ++p)
      orow[p] = fmaxf(acc[p][o] + bb, 0.f);
  }
}

// ---- conv3 v3: block = frame; x frame AND transposed weights in LDS ----
__global__ __launch_bounds__(256) void conv3_kernel(
    const float* __restrict__ a2, const float* __restrict__ w,
    const float* __restrict__ bias, float* __restrict__ out) {
  __shared__ float wTs[144 * 65];      // 37440 B
  __shared__ float xs2[64 * 36];       // 9216 B
  const int n = blockIdx.x;
  const int t = threadIdx.x;
  const int oy = t >> 6;               // 0..3
  const int oc = t & 63;

  const float* ab = a2 + (size_t)n * 2304;
  #pragma unroll
  for (int i = 0; i < 9; ++i) xs2[i * 256 + t] = ab[i * 256 + t];

  float acc[4] = {};
  for (int c0 = 0; c0 < 64; c0 += 16) {
    __syncthreads();
    #pragma unroll
    for (int i = 0; i < 36; ++i) {
      const int lin = i * 256 + t;
      const int ocs = lin / 144;
      const int rem = lin - ocs * 144;
      wTs[rem * 65 + ocs] = w[(size_t)ocs * 576 + c0 * 9 + rem];
    }
    __syncthreads();
    for (int cc = 0; cc < 16; ++cc) {
      const float* xb = &xs2[(c0 + cc) * 36];
      #pragma unroll
      for (int ky = 0; ky < 3; ++ky) {
        const float* xr = xb + (oy + ky) * 6;
        const float2 x01 = *(const float2*)(xr);
        const float2 x23 = *(const float2*)(xr + 2);
        const float2 x45 = *(const float2*)(xr + 4);
        const float xv[6] = {x01.x, x01.y, x23.x, x23.y, x45.x, x45.y};
        const float* wrow = &wTs[(cc * 9 + ky * 3) * 65 + oc];
        const float wk0 = wrow[0], wk1 = wrow[65], wk2 = wrow[130];
        #pragma unroll
        for (int p = 0; p < 4; ++p)
          acc[p] = fmaf(xv[p], wk0,
                   fmaf(xv[p + 1], wk1,
                   fmaf(xv[p + 2], wk2, acc[p])));
      }
    }
  }
  const float bb = bias[oc];
  float* orow = out + ((size_t)n * 64 + oc) * 16 + oy * 4;
  #pragma unroll
  for (int p = 0; p < 4; ++p)
    orow[p] = fmaxf(acc[p] + bb, 0.f);
}

// ---- generic GEMM: C[M,N] = act(A[M,K] @ B[N,K]^T + bias1 (+bias2)) ----
__global__ __launch_bounds__(256) void gemm_bias_kernel(
    const float* __restrict__ A, const float* __restrict__ B,
    const float* __restrict__ bias1, const float* __restrict__ bias2,
    float* __restrict__ C, int M, int N, int K, int relu) {
  __shared__ float As[16][68];
  __shared__ float Bs[16][68];
  const int t = threadIdx.x;
  const int n0 = blockIdx.x * 64;
  const int m0 = blockIdx.y * 64;
  const int ty = t >> 4, tx = t & 15;
  const int sl = t >> 2, kq = (t & 3) * 4;

  float acc[4][4] = {};

  for (int k0 = 0; k0 < K; k0 += 16) {
    float4 av = *(const float4*)(A + (size_t)(m0 + sl) * K + k0 + kq);
    float4 bv = *(const float4*)(B + (size_t)(n0 + sl) * K + k0 + kq);
    As[kq + 0][sl] = av.x; As[kq + 1][sl] = av.y;
    As[kq + 2][sl] = av.z; As[kq + 3][sl] = av.w;
    Bs[kq + 0][sl] = bv.x; Bs[kq + 1][sl] = bv.y;
    Bs[kq + 2][sl] = bv.z; Bs[kq + 3][sl] = bv.w;
    __syncthreads();
    #pragma unroll
    for (int kk = 0; kk < 16; ++kk) {
      float4 a = *(const float4*)&As[kk][ty * 4];
      float4 b = *(const float4*)&Bs[kk][tx * 4];
      float ar[4] = {a.x, a.y, a.z, a.w};
      float br[4] = {b.x, b.y, b.z, b.w};
      #pragma unroll
      for (int i = 0; i < 4; ++i)
        #pragma unroll
        for (int j = 0; j < 4; ++j)
          acc[i][j] = fmaf(ar[i], br[j], acc[i][j]);
    }
    __syncthreads();
  }

  #pragma unroll
  for (int i = 0; i < 4; ++i) {
    int m = m0 + ty * 4 + i;
    #pragma unroll
    for (int j = 0; j < 4; ++j) {
      int n = n0 + tx * 4 + j;
      float v = acc[i][j] + bias1[n];
      if (bias2) v += bias2[n];
      if (relu) v = fmaxf(v, 0.f);
      C[(size_t)m * N + n] = v;
    }
  }
}

// ---------------------------------------------------------------------------
// LSTM v4: weight-resident pair-split scan.
//   Old design streamed Wh (512 KB fp16) from L2 through L1 every step per
//   env-CU: ~3.8 us/step floor at ~56 B/cy/CU (measured 4.68 us/step).
//   The register file is the only level with enough BW, so: 64 blocks =
//   (env e, side s). Block owns gate rows {g*256 + s*128 + j, j<128}; one
//   thread = one full row, 128 half2 of Wh pinned in VGPRs for all 128 steps.
//   Full-K dots -> complete gate sums (no partial exchange); cell update is
//   local to the block's own h-slice. The ONLY cross-block traffic per step
//   is the partner's 256 B h-half, via a pairwise device-scope handshake
//   (release fence + atomic arrive + spin + acquire fence). Parity
//   double-buffered exchange; step-indexed counters zeroed per launch.
//   Pairs mapped (b, b+32) so partners tend to land on the same XCD.
// ---------------------------------------------------------------------------
__global__ __launch_bounds__(512, 2) void lstm_pair_kernel(
    const float* __restrict__ gates_pre, const float* __restrict__ wh,
    const float* __restrict__ done, const float* __restrict__ h0,
    const float* __restrict__ c0, float* __restrict__ outs,
    unsigned int* __restrict__ cnt, unsigned int* __restrict__ h2x) {
  __shared__ alignas(16) unsigned int h2s[128];  // masked h (fp16x2), this step
  __shared__ float pLDS[512];                    // full gate sums (incl. pre)
  __shared__ float cLDS[128];                    // cell state, own slice
  __shared__ unsigned short hOut16[128];         // new h as fp16

  const int e = blockIdx.x & 31;     // env
  const int s = blockIdx.x >> 5;     // side (0: j<128, 1: j>=128)
  const int rr = (int)threadIdx.x;   // 0..511
  const int g = rr >> 7;             // gate 0..3
  const int j = rr & 127;
  const int R = g * 256 + s * 128 + j;   // global Wh row owned by this thread

  // ---- one-time: pin this row of Wh in VGPRs as 128 half2 ----
  half2_t w2[128];
  {
    const float4* wr = (const float4*)(wh + (size_t)R * 256);
    #pragma unroll
    for (int i = 0; i < 64; ++i) {
      float4 f = wr[i];
      half2_t a, b;
      a.x = (_Float16)f.x; a.y = (_Float16)f.y;
      b.x = (_Float16)f.z; b.y = (_Float16)f.w;
      w2[2 * i] = a; w2[2 * i + 1] = b;
    }
  }

  // ---- init: full masked h0 (both halves), own c0 slice ----
  if (rr < 128) {
    const float m0 = 1.f - done[e];                 // done[0*32+e]
    float2 h = *(const float2*)(h0 + e * 256 + 2 * rr);
    half2_t hh; hh.x = (_Float16)(h.x * m0); hh.y = (_Float16)(h.y * m0);
    h2s[rr] = __builtin_bit_cast(unsigned int, hh);
    cLDS[rr] = c0[e * 256 + s * 128 + rr];
  }
  __syncthreads();

  const int my_off = s * 64;         // this block's h2-word range in exchange
  const int pa_off = 64 - my_off;    // partner's

  for (int st = 0; st < 128; ++st) {
    // prefetch (constant inputs; latency hides under the dot phase)
    const float gp = gates_pre[(size_t)(st * 32 + e) * 1024 + R];
    const float d_cur = done[st * 32 + e];
    const float d_nxt = (st < 127) ? done[(st + 1) * 32 + e] : 0.f;

    // ---- dot: full row (K=256) vs broadcast h in LDS, 4 indep chains ----
    float a0 = 0.f, a1 = 0.f, a2 = 0.f, a3 = 0.f;
    #pragma unroll
    for (int i = 0; i < 8; ++i) {
      const uint4 hv0 = *(const uint4*)&h2s[4 * i];
      const uint4 hv1 = *(const uint4*)&h2s[32 + 4 * i];
      const uint4 hv2 = *(const uint4*)&h2s[64 + 4 * i];
      const uint4 hv3 = *(const uint4*)&h2s[96 + 4 * i];
      a0 = __builtin_amdgcn_fdot2(w2[4 * i + 0], __builtin_bit_cast(half2_t, hv0.x), a0, false);
      a1 = __builtin_amdgcn_fdot2(w2[32 + 4 * i + 0], __builtin_bit_cast(half2_t, hv1.x), a1, false);
      a2 = __builtin_amdgcn_fdot2(w2[64 + 4 * i + 0], __builtin_bit_cast(half2_t, hv2.x), a2, false);
      a3 = __builtin_amdgcn_fdot2(w2[96 + 4 * i + 0], __builtin_bit_cast(half2_t, hv3.x), a3, false);
      a0 = __builtin_amdgcn_fdot2(w2[4 * i + 1], __builtin_bit_cast(half2_t, hv0.y), a0, false);
      a1 = __builtin_amdgcn_fdot2(w2[32 + 4 * i + 1], __builtin_bit_cast(half2_t, hv1.y), a1, false);
      a2 = __builtin_amdgcn_fdot2(w2[64 + 4 * i + 1], __builtin_bit_cast(half2_t, hv2.y), a2, false);
      a3 = __builtin_amdgcn_fdot2(w2[96 + 4 * i + 1], __builtin_bit_cast(half2_t, hv3.y), a3, false);
      a0 = __builtin_amdgcn_fdot2(w2[4 * i + 2], __builtin_bit_cast(half2_t, hv0.z), a0, false);
      a1 = __builtin_amdgcn_fdot2(w2[32 + 4 * i + 2], __builtin_bit_cast(half2_t, hv1.z), a1, false);
      a2 = __builtin_amdgcn_fdot2(w2[64 + 4 * i + 2], __builtin_bit_cast(half2_t, hv2.z), a2, false);
      a3 = __builtin_amdgcn_fdot2(w2[96 + 4 * i + 2], __builtin_bit_cast(half2_t, hv3.z), a3, false);
      a0 = __builtin_amdgcn_fdot2(w2[4 * i + 3], __builtin_bit_cast(half2_t, hv0.w), a0, false);
      a1 = __builtin_amdgcn_fdot2(w2[32 + 4 * i + 3], __builtin_bit_cast(half2_t, hv1.w), a1, false);
      a2 = __builtin_amdgcn_fdot2(w2[64 + 4 * i + 3], __builtin_bit_cast(half2_t, hv2.w), a2, false);
      a3 = __builtin_amdgcn_fdot2(w2[96 + 4 * i + 3], __builtin_bit_cast(half2_t, hv3.w), a3, false);
    }
    pLDS[rr] = a0 + a1 + a2 + a3 + gp;
    __syncthreads();

    // ---- cell update (own slice only; gates are complete sums) ----
    if (rr < 128) {
      const float m = 1.f - d_cur;
      float c = cLDS[rr] * m;
      float iv = pLDS[rr];
      float fv = pLDS[128 + rr];
      float gv = pLDS[256 + rr];
      float ov = pLDS[384 + rr];
      float ig = 1.f / (1.f + expf(-iv));
      float fg = 1.f / (1.f + expf(-fv));
      float og = 1.f / (1.f + expf(-ov));
      float cn = fmaf(fg, c, ig * tanhf(gv));
      float hn = og * tanhf(cn);
      cLDS[rr] = cn;
      outs[(size_t)st * 8192 + e * 256 + s * 128 + rr] = hn;
      hOut16[rr] = __builtin_bit_cast(unsigned short, (_Float16)hn);
    }
    __syncthreads();

    // ---- pairwise h exchange (skip after last step) ----
    if (st < 127) {
      unsigned int* hx = h2x + (st & 1) * 4096 + e * 128;  // parity dbuf
      if (rr < 64) {                 // exactly wave 0
        unsigned int w = (unsigned int)hOut16[2 * rr] |
                         ((unsigned int)hOut16[2 * rr + 1] << 16);
        hx[my_off + rr] = w;                            // publish own half
        h2s[my_off + rr] = (d_nxt != 0.f) ? 0u : w;     // own half, masked
        __builtin_amdgcn_fence(__ATOMIC_RELEASE, "agent");
      }
      __syncthreads();
      if (rr == 0) {
        unsigned int* cp = &cnt[st * 32 + e];
        __hip_atomic_fetch_add(cp, 1u, __ATOMIC_RELAXED, __HIP_MEMORY_SCOPE_AGENT);
        while (__hip_atomic_load(cp, __ATOMIC_RELAXED, __HIP_MEMORY_SCOPE_AGENT) < 2u)
          __builtin_amdgcn_s_sleep(1);
      }
      __syncthreads();
      if (rr < 64) {
        __builtin_amdgcn_fence(__ATOMIC_ACQUIRE, "agent");
        unsigned int w = hx[pa_off + rr];               // partner half
        h2s[pa_off + rr] = (d_nxt != 0.f) ? 0u : w;
      }
      __syncthreads();
    }
  }
}

// ---- heads ----
__global__ __launch_bounds__(256) void heads_kernel(
    const float* __restrict__ outs, const float* __restrict__ aw,
    const float* __restrict__ ab, const float* __restrict__ cw,
    const float* __restrict__ cb, float* __restrict__ out) {
  __shared__ float rs[8 * 256];
  const int t = threadIdx.x;
  const int r0 = blockIdx.x * 8;
  for (int i = 0; i < 8; ++i)
    rs[i * 256 + t] = outs[(size_t)(r0 + i) * 256 + t];
  __syncthreads();
  int r = t >> 5, c = t & 31;
  if (c < 19) {
    const float* wr = (c < 18) ? (aw + c * 256) : cw;
    float bias = (c < 18) ? ab[c] : cb[0];
    float acc = 0.f;
    for (int k = 0; k < 256; ++k) acc = fmaf(rs[r * 256 + k], wr[k], acc);
    out[(size_t)(r0 + r) * 19 + c] = acc + bias;
  }
}

extern "C" void kernel_launch(void* const* d_in, const int* in_sizes, int n_in,
                              void* d_out, int out_size, void* d_ws, size_t ws_size,
                              hipStream_t stream) {
  (void)in_sizes; (void)n_in; (void)out_size;
  const float* x    = (const float*)d_in[0];
  const float* done = (const float*)d_in[1];
  const float* h0   = (const float*)d_in[2];
  const float* c0   = (const float*)d_in[3];
  const float* w1   = (const float*)d_in[4];
  const float* b1   = (const float*)d_in[5];
  const float* w2   = (const float*)d_in[6];
  const float* b2   = (const float*)d_in[7];
  const float* w3   = (const float*)d_in[8];
  const float* b3   = (const float*)d_in[9];
  const float* fcw  = (const float*)d_in[10];
  const float* fcb  = (const float*)d_in[11];
  const float* wi   = (const float*)d_in[12];
  const float* wh   = (const float*)d_in[13];
  const float* bi   = (const float*)d_in[14];
  const float* bh   = (const float*)d_in[15];
  const float* aw   = (const float*)d_in[16];
  const float* abv  = (const float*)d_in[17];
  const float* cw   = (const float*)d_in[18];
  const float* cbv  = (const float*)d_in[19];
  float* out = (float*)d_out;

  const size_t SZ_A1 = 29491200, SZ_A2 = 9437184, SZ_A3 = 4194304;
  const size_t SZ_F = 2097152, SZ_G = 4194304, SZ_O = 1048576;
  const size_t SZ_SYNC = 131072;       // sync counters + h exchange (floats)
  const size_t need =
      (SZ_A1 + SZ_A2 + SZ_A3 + SZ_F + SZ_G + SZ_O + SZ_SYNC) * 4;
  if (ws_size < need) return;

  float* wsp  = (float*)d_ws;
  float* a1   = wsp;
  float* a2   = a1 + SZ_A1;
  float* a3   = a2 + SZ_A2;
  float* feats= a3 + SZ_A3;
  float* gts  = feats + SZ_F;
  float* outs = gts + SZ_G;
  unsigned int* cnt = (unsigned int*)(outs + SZ_O);  // 128*32 u32 = 16 KB
  unsigned int* h2x = cnt + 4096;                    // 2*32*128 u32 = 32 KB

  (void)hipMemsetAsync(cnt, 0, 4096 * sizeof(unsigned int), stream);
  conv1_kernel<<<4096, 256, 0, stream>>>(x, w1, b1, a1);
  conv2_kernel<<<4096, 192, 0, stream>>>(a1, w2, b2, a2);
  conv3_kernel<<<4096, 256, 0, stream>>>(a2, w3, b3, a3);
  gemm_bias_kernel<<<dim3(8, 64), 256, 0, stream>>>(a3, fcw, fcb, nullptr, feats,
                                                    4096, 512, 1024, 1);
  gemm_bias_kernel<<<dim3(16, 64), 256, 0, stream>>>(feats, wi, bi, bh, gts,
                                                     4096, 1024, 512, 0);
  lstm_pair_kernel<<<64, 512, 0, stream>>>(gts, wh, done, h0, c0, outs, cnt, h2x);
  heads_kernel<<<512, 256, 0, stream>>>(outs, aw, abv, cw, cbv, out);
}

// Round 3
// 1444.494 us; speedup vs baseline: 1.3216x; 1.2022x over previous
//
#include <hip/hip_runtime.h>
#include <math.h>

// ---------------------------------------------------------------------------
// Shapes: T=128, N=32 -> TN=4096
//  x: (4096,4,64,64) f32 | conv1 (32,4,8,8)s4 -> a1 (4096,32,15,15)
//  conv2 (64,32,4,4)s2 -> a2 (4096,64,6,6) | conv3 (64,64,3,3)s1 -> a3 (4096,1024)
//  fc (512,1024) -> feats (4096,512) | lstm wi(1024,512) wh(1024,256) H=256
//  heads: actor(18,256) critic(1,256) -> out (4096,19)
// ---------------------------------------------------------------------------

typedef _Float16 half2_t __attribute__((ext_vector_type(2)));

__device__ __forceinline__ float f4c(float4 v, int k) {
  return k == 0 ? v.x : (k == 1 ? v.y : (k == 2 ? v.z : v.w));
}

// ---- weight pre-pack: lane-major layouts so weight loads coalesce ----------
// conv1: wp1[((c*8+ky)*4+h)*16+og] = (w(2h,oc0), w(2h,oc1), w(2h+1,oc0), w(2h+1,oc1))
//        oc0=2*og.  2048 float4.
// conv2: wp2[((c*4+ky)*2+h)*32+op] = (w(2h,oc0), w(2h,oc1), w(2h+1,oc0), w(2h+1,oc1))
//        oc0=2*op.  8192 float4.
__global__ __launch_bounds__(256) void pack_w_kernel(
    const float* __restrict__ w1, const float* __restrict__ w2,
    float4* __restrict__ wp1, float4* __restrict__ wp2) {
  const int i = blockIdx.x * 256 + threadIdx.x;
  if (i < 2048) {
    const int og = i & 15, j = i >> 4;
    const int h = j & 3, jj = j >> 2;
    const int ky = jj & 7, c = jj >> 3;
    const float* b0 = w1 + (2 * og) * 256 + c * 64 + ky * 8 + 2 * h;
    const float* b1 = b0 + 256;
    wp1[i] = make_float4(b0[0], b1[0], b0[1], b1[1]);
  } else if (i < 10240) {
    const int i2 = i - 2048;
    const int op = i2 & 31, j = i2 >> 5;
    const int h = j & 1, jj = j >> 1;
    const int ky = jj & 3, c = jj >> 2;
    const float* b0 = w2 + (2 * op) * 512 + c * 16 + ky * 4 + 2 * h;
    const float* b1 = b0 + 512;
    wp2[i2] = make_float4(b0[0], b1[0], b0[1], b1[1]);
  }
}

// ---- conv1 v4: block = frame; packed coalesced weight loads ----
__global__ __launch_bounds__(256) void conv1_kernel(
    const float* __restrict__ x, const float4* __restrict__ wp1,
    const float* __restrict__ bias, float* __restrict__ out) {
  __shared__ float xs[64 * 68];      // 17408 B, one input channel
  const int n = blockIdx.x;
  const int t = threadIdx.x;
  const int oy = t >> 4;             // 0..15 (15 idle in compute)
  const int og = t & 15;
  const int oc0 = og * 2;

  float acc[15][2] = {};
  const float4* xg = (const float4*)(x + (size_t)n * 16384);

  for (int c = 0; c < 4; ++c) {
    __syncthreads();                 // previous channel consumed
    #pragma unroll
    for (int i = 0; i < 4; ++i) {    // stage 1024 float4
      int f4 = i * 256 + t;
      int y = f4 >> 4, xq = f4 & 15;
      *(float4*)&xs[y * 68 + xq * 4] = xg[c * 1024 + f4];
    }
    __syncthreads();
    if (oy < 15) {
      for (int ky = 0; ky < 8; ++ky) {
        const float* xr = &xs[(4 * oy + ky) * 68];
        const float4* wb4 = wp1 + ((c * 8 + ky) * 4) * 16 + og;
        const float4 wv0 = wb4[0];
        const float4 wv1 = wb4[16];
        const float4 wv2 = wb4[32];
        const float4 wv3 = wb4[48];
        const float4 wv[4] = {wv0, wv1, wv2, wv3};
        {
          float4 xv[9];
          #pragma unroll
          for (int i = 0; i < 9; ++i) xv[i] = *(const float4*)(xr + 4 * i);
          #pragma unroll
          for (int h = 0; h < 4; ++h) {
            #pragma unroll
            for (int p = 0; p < 8; ++p) {
              const int k = 4 * p + 2 * h;
              const float xa = f4c(xv[k >> 2], k & 3);
              const float xb = f4c(xv[(k + 1) >> 2], (k + 1) & 3);
              acc[p][0] = fmaf(xa, wv[h].x, fmaf(xb, wv[h].z, acc[p][0]));
              acc[p][1] = fmaf(xa, wv[h].y, fmaf(xb, wv[h].w, acc[p][1]));
            }
          }
        }
        {
          float4 yv[8];
          #pragma unroll
          for (int i = 0; i < 8; ++i) yv[i] = *(const float4*)(xr + 32 + 4 * i);
          #pragma unroll
          for (int h = 0; h < 4; ++h) {
            #pragma unroll
            for (int p = 8; p < 15; ++p) {
              const int q = 4 * p + 2 * h - 32;
              const float xa = f4c(yv[q >> 2], q & 3);
              const float xb = f4c(yv[(q + 1) >> 2], (q + 1) & 3);
              acc[p][0] = fmaf(xa, wv[h].x, fmaf(xb, wv[h].z, acc[p][0]));
              acc[p][1] = fmaf(xa, wv[h].y, fmaf(xb, wv[h].w, acc[p][1]));
            }
          }
        }
      }
    }
  }
  if (oy < 15) {
    const float inv = 1.f / 255.f;
    #pragma unroll
    for (int o = 0; o < 2; ++o) {
      const int oc = oc0 + o;
      const float bb = bias[oc];
      float* orow = out + ((size_t)n * 32 + oc) * 225 + oy * 15;
      #pragma unroll
      for (int p = 0; p < 15; ++p)
        orow[p] = fmaxf(fmaf(acc[p][o], inv, bb), 0.f);
    }
  }
}

// ---- conv2 v4: block = frame (192 thr); packed coalesced weight loads ----
__global__ __launch_bounds__(192) void conv2_kernel(
    const float* __restrict__ a1, const float4* __restrict__ wp2,
    const float* __restrict__ bias, float* __restrict__ out) {
  __shared__ float xs[32 * 15 * 16];   // 30720 B
  const int n = blockIdx.x;
  const int t = threadIdx.x;           // 0..191
  const float* ag = a1 + (size_t)n * 7200;
  for (int i = 0; i < 38; ++i) {
    int idx = i * 192 + t;
    if (idx < 7200) {
      int c = idx / 225, rem = idx - c * 225;
      int row = rem / 15, col = rem - row * 15;
      xs[(c * 15 + row) * 16 + col] = ag[idx];
    }
  }
  __syncthreads();

  const int oy = t >> 5;               // 0..5
  const int op = t & 31;
  const int oc0 = op * 2;
  float acc[6][2] = {};

  for (int c = 0; c < 32; ++c) {
    #pragma unroll
    for (int ky = 0; ky < 4; ++ky) {
      const float* xr = &xs[(c * 15 + 2 * oy + ky) * 16];
      const float4 xa = *(const float4*)(xr);
      const float4 xb = *(const float4*)(xr + 4);
      const float4 xc = *(const float4*)(xr + 8);
      const float2 xd = *(const float2*)(xr + 12);
      const float xv[14] = {xa.x, xa.y, xa.z, xa.w, xb.x, xb.y, xb.z, xb.w,
                            xc.x, xc.y, xc.z, xc.w, xd.x, xd.y};
      const float4 wA = wp2[((c * 4 + ky) * 2 + 0) * 32 + op];
      const float4 wB = wp2[((c * 4 + ky) * 2 + 1) * 32 + op];
      #pragma unroll
      for (int p = 0; p < 6; ++p) {
        const int b = 2 * p;
        acc[p][0] = fmaf(xv[b], wA.x, fmaf(xv[b + 1], wA.z,
                    fmaf(xv[b + 2], wB.x, fmaf(xv[b + 3], wB.z, acc[p][0]))));
        acc[p][1] = fmaf(xv[b], wA.y, fmaf(xv[b + 1], wA.w,
                    fmaf(xv[b + 2], wB.y, fmaf(xv[b + 3], wB.w, acc[p][1]))));
      }
    }
  }
  #pragma unroll
  for (int o = 0; o < 2; ++o) {
    const int oc = oc0 + o;
    const float bb = bias[oc];
    float* orow = out + ((size_t)n * 64 + oc) * 36 + oy * 6;
    #pragma unroll
    for (int p = 0; p < 6; ++p)
      orow[p] = fmaxf(acc[p][o] + bb, 0.f);
  }
}

// ---- conv3 v3: block = frame; x frame AND transposed weights in LDS ----
__global__ __launch_bounds__(256) void conv3_kernel(
    const float* __restrict__ a2, const float* __restrict__ w,
    const float* __restrict__ bias, float* __restrict__ out) {
  __shared__ float wTs[144 * 65];      // 37440 B
  __shared__ float xs2[64 * 36];       // 9216 B
  const int n = blockIdx.x;
  const int t = threadIdx.x;
  const int oy = t >> 6;               // 0..3
  const int oc = t & 63;

  const float* ab = a2 + (size_t)n * 2304;
  #pragma unroll
  for (int i = 0; i < 9; ++i) xs2[i * 256 + t] = ab[i * 256 + t];

  float acc[4] = {};
  for (int c0 = 0; c0 < 64; c0 += 16) {
    __syncthreads();
    #pragma unroll
    for (int i = 0; i < 36; ++i) {
      const int lin = i * 256 + t;
      const int ocs = lin / 144;
      const int rem = lin - ocs * 144;
      wTs[rem * 65 + ocs] = w[(size_t)ocs * 576 + c0 * 9 + rem];
    }
    __syncthreads();
    for (int cc = 0; cc < 16; ++cc) {
      const float* xb = &xs2[(c0 + cc) * 36];
      #pragma unroll
      for (int ky = 0; ky < 3; ++ky) {
        const float* xr = xb + (oy + ky) * 6;
        const float2 x01 = *(const float2*)(xr);
        const float2 x23 = *(const float2*)(xr + 2);
        const float2 x45 = *(const float2*)(xr + 4);
        const float xv[6] = {x01.x, x01.y, x23.x, x23.y, x45.x, x45.y};
        const float* wrow = &wTs[(cc * 9 + ky * 3) * 65 + oc];
        const float wk0 = wrow[0], wk1 = wrow[65], wk2 = wrow[130];
        #pragma unroll
        for (int p = 0; p < 4; ++p)
          acc[p] = fmaf(xv[p], wk0,
                   fmaf(xv[p + 1], wk1,
                   fmaf(xv[p + 2], wk2, acc[p])));
      }
    }
  }
  const float bb = bias[oc];
  float* orow = out + ((size_t)n * 64 + oc) * 16 + oy * 4;
  #pragma unroll
  for (int p = 0; p < 4; ++p)
    orow[p] = fmaxf(acc[p] + bb, 0.f);
}

// ---- generic GEMM: C[M,N] = act(A[M,K] @ B[N,K]^T + bias1 (+bias2)) ----
__global__ __launch_bounds__(256) void gemm_bias_kernel(
    const float* __restrict__ A, const float* __restrict__ B,
    const float* __restrict__ bias1, const float* __restrict__ bias2,
    float* __restrict__ C, int M, int N, int K, int relu) {
  __shared__ float As[16][68];
  __shared__ float Bs[16][68];
  const int t = threadIdx.x;
  const int n0 = blockIdx.x * 64;
  const int m0 = blockIdx.y * 64;
  const int ty = t >> 4, tx = t & 15;
  const int sl = t >> 2, kq = (t & 3) * 4;

  float acc[4][4] = {};

  for (int k0 = 0; k0 < K; k0 += 16) {
    float4 av = *(const float4*)(A + (size_t)(m0 + sl) * K + k0 + kq);
    float4 bv = *(const float4*)(B + (size_t)(n0 + sl) * K + k0 + kq);
    As[kq + 0][sl] = av.x; As[kq + 1][sl] = av.y;
    As[kq + 2][sl] = av.z; As[kq + 3][sl] = av.w;
    Bs[kq + 0][sl] = bv.x; Bs[kq + 1][sl] = bv.y;
    Bs[kq + 2][sl] = bv.z; Bs[kq + 3][sl] = bv.w;
    __syncthreads();
    #pragma unroll
    for (int kk = 0; kk < 16; ++kk) {
      float4 a = *(const float4*)&As[kk][ty * 4];
      float4 b = *(const float4*)&Bs[kk][tx * 4];
      float ar[4] = {a.x, a.y, a.z, a.w};
      float br[4] = {b.x, b.y, b.z, b.w};
      #pragma unroll
      for (int i = 0; i < 4; ++i)
        #pragma unroll
        for (int j = 0; j < 4; ++j)
          acc[i][j] = fmaf(ar[i], br[j], acc[i][j]);
    }
    __syncthreads();
  }

  #pragma unroll
  for (int i = 0; i < 4; ++i) {
    int m = m0 + ty * 4 + i;
    #pragma unroll
    for (int j = 0; j < 4; ++j) {
      int n = n0 + tx * 4 + j;
      float v = acc[i][j] + bias1[n];
      if (bias2) v += bias2[n];
      if (relu) v = fmaxf(v, 0.f);
      C[(size_t)m * N + n] = v;
    }
  }
}

// ---------------------------------------------------------------------------
// LSTM v4: weight-resident pair-split scan (see round-2 notes).
// ---------------------------------------------------------------------------
__global__ __launch_bounds__(512, 2) void lstm_pair_kernel(
    const float* __restrict__ gates_pre, const float* __restrict__ wh,
    const float* __restrict__ done, const float* __restrict__ h0,
    const float* __restrict__ c0, float* __restrict__ outs,
    unsigned int* __restrict__ cnt, unsigned int* __restrict__ h2x) {
  __shared__ alignas(16) unsigned int h2s[128];  // masked h (fp16x2), this step
  __shared__ float pLDS[512];                    // full gate sums (incl. pre)
  __shared__ float cLDS[128];                    // cell state, own slice
  __shared__ unsigned short hOut16[128];         // new h as fp16

  const int e = blockIdx.x & 31;     // env
  const int s = blockIdx.x >> 5;     // side (0: j<128, 1: j>=128)
  const int rr = (int)threadIdx.x;   // 0..511
  const int g = rr >> 7;             // gate 0..3
  const int j = rr & 127;
  const int R = g * 256 + s * 128 + j;   // global Wh row owned by this thread

  // ---- one-time: pin this row of Wh in VGPRs as 128 half2 ----
  half2_t w2[128];
  {
    const float4* wr = (const float4*)(wh + (size_t)R * 256);
    #pragma unroll
    for (int i = 0; i < 64; ++i) {
      float4 f = wr[i];
      half2_t a, b;
      a.x = (_Float16)f.x; a.y = (_Float16)f.y;
      b.x = (_Float16)f.z; b.y = (_Float16)f.w;
      w2[2 * i] = a; w2[2 * i + 1] = b;
    }
  }

  // ---- init: full masked h0 (both halves), own c0 slice ----
  if (rr < 128) {
    const float m0 = 1.f - done[e];                 // done[0*32+e]
    float2 h = *(const float2*)(h0 + e * 256 + 2 * rr);
    half2_t hh; hh.x = (_Float16)(h.x * m0); hh.y = (_Float16)(h.y * m0);
    h2s[rr] = __builtin_bit_cast(unsigned int, hh);
    cLDS[rr] = c0[e * 256 + s * 128 + rr];
  }
  __syncthreads();

  const int my_off = s * 64;         // this block's h2-word range in exchange
  const int pa_off = 64 - my_off;    // partner's

  for (int st = 0; st < 128; ++st) {
    // prefetch (constant inputs; latency hides under the dot phase)
    const float gp = gates_pre[(size_t)(st * 32 + e) * 1024 + R];
    const float d_cur = done[st * 32 + e];
    const float d_nxt = (st < 127) ? done[(st + 1) * 32 + e] : 0.f;

    // ---- dot: full row (K=256) vs broadcast h in LDS, 4 indep chains ----
    float a0 = 0.f, a1 = 0.f, a2 = 0.f, a3 = 0.f;
    #pragma unroll
    for (int i = 0; i < 8; ++i) {
      const uint4 hv0 = *(const uint4*)&h2s[4 * i];
      const uint4 hv1 = *(const uint4*)&h2s[32 + 4 * i];
      const uint4 hv2 = *(const uint4*)&h2s[64 + 4 * i];
      const uint4 hv3 = *(const uint4*)&h2s[96 + 4 * i];
      a0 = __builtin_amdgcn_fdot2(w2[4 * i + 0], __builtin_bit_cast(half2_t, hv0.x), a0, false);
      a1 = __builtin_amdgcn_fdot2(w2[32 + 4 * i + 0], __builtin_bit_cast(half2_t, hv1.x), a1, false);
      a2 = __builtin_amdgcn_fdot2(w2[64 + 4 * i + 0], __builtin_bit_cast(half2_t, hv2.x), a2, false);
      a3 = __builtin_amdgcn_fdot2(w2[96 + 4 * i + 0], __builtin_bit_cast(half2_t, hv3.x), a3, false);
      a0 = __builtin_amdgcn_fdot2(w2[4 * i + 1], __builtin_bit_cast(half2_t, hv0.y), a0, false);
      a1 = __builtin_amdgcn_fdot2(w2[32 + 4 * i + 1], __builtin_bit_cast(half2_t, hv1.y), a1, false);
      a2 = __builtin_amdgcn_fdot2(w2[64 + 4 * i + 1], __builtin_bit_cast(half2_t, hv2.y), a2, false);
      a3 = __builtin_amdgcn_fdot2(w2[96 + 4 * i + 1], __builtin_bit_cast(half2_t, hv3.y), a3, false);
      a0 = __builtin_amdgcn_fdot2(w2[4 * i + 2], __builtin_bit_cast(half2_t, hv0.z), a0, false);
      a1 = __builtin_amdgcn_fdot2(w2[32 + 4 * i + 2], __builtin_bit_cast(half2_t, hv1.z), a1, false);
      a2 = __builtin_amdgcn_fdot2(w2[64 + 4 * i + 2], __builtin_bit_cast(half2_t, hv2.z), a2, false);
      a3 = __builtin_amdgcn_fdot2(w2[96 + 4 * i + 2], __builtin_bit_cast(half2_t, hv3.z), a3, false);
      a0 = __builtin_amdgcn_fdot2(w2[4 * i + 3], __builtin_bit_cast(half2_t, hv0.w), a0, false);
      a1 = __builtin_amdgcn_fdot2(w2[32 + 4 * i + 3], __builtin_bit_cast(half2_t, hv1.w), a1, false);
      a2 = __builtin_amdgcn_fdot2(w2[64 + 4 * i + 3], __builtin_bit_cast(half2_t, hv2.w), a2, false);
      a3 = __builtin_amdgcn_fdot2(w2[96 + 4 * i + 3], __builtin_bit_cast(half2_t, hv3.w), a3, false);
    }
    pLDS[rr] = a0 + a1 + a2 + a3 + gp;
    __syncthreads();

    // ---- cell update (own slice only; gates are complete sums) ----
    if (rr < 128) {
      const float m = 1.f - d_cur;
      float c = cLDS[rr] * m;
      float iv = pLDS[rr];
      float fv = pLDS[128 + rr];
      float gv = pLDS[256 + rr];
      float ov = pLDS[384 + rr];
      float ig = 1.f / (1.f + expf(-iv));
      float fg = 1.f / (1.f + expf(-fv));
      float og = 1.f / (1.f + expf(-ov));
      float cn = fmaf(fg, c, ig * tanhf(gv));
      float hn = og * tanhf(cn);
      cLDS[rr] = cn;
      outs[(size_t)st * 8192 + e * 256 + s * 128 + rr] = hn;
      hOut16[rr] = __builtin_bit_cast(unsigned short, (_Float16)hn);
    }
    __syncthreads();

    // ---- pairwise h exchange (skip after last step) ----
    if (st < 127) {
      unsigned int* hx = h2x + (st & 1) * 4096 + e * 128;  // parity dbuf
      if (rr < 64) {                 // exactly wave 0
        unsigned int w = (unsigned int)hOut16[2 * rr] |
                         ((unsigned int)hOut16[2 * rr + 1] << 16);
        hx[my_off + rr] = w;                            // publish own half
        h2s[my_off + rr] = (d_nxt != 0.f) ? 0u : w;     // own half, masked
        __builtin_amdgcn_fence(__ATOMIC_RELEASE, "agent");
      }
      __syncthreads();
      if (rr == 0) {
        unsigned int* cp = &cnt[st * 32 + e];
        __hip_atomic_fetch_add(cp, 1u, __ATOMIC_RELAXED, __HIP_MEMORY_SCOPE_AGENT);
        while (__hip_atomic_load(cp, __ATOMIC_RELAXED, __HIP_MEMORY_SCOPE_AGENT) < 2u)
          __builtin_amdgcn_s_sleep(1);
      }
      __syncthreads();
      if (rr < 64) {
        __builtin_amdgcn_fence(__ATOMIC_ACQUIRE, "agent");
        unsigned int w = hx[pa_off + rr];               // partner half
        h2s[pa_off + rr] = (d_nxt != 0.f) ? 0u : w;
      }
      __syncthreads();
    }
  }
}

// ---- heads ----
__global__ __launch_bounds__(256) void heads_kernel(
    const float* __restrict__ outs, const float* __restrict__ aw,
    const float* __restrict__ ab, const float* __restrict__ cw,
    const float* __restrict__ cb, float* __restrict__ out) {
  __shared__ float rs[8 * 256];
  const int t = threadIdx.x;
  const int r0 = blockIdx.x * 8;
  for (int i = 0; i < 8; ++i)
    rs[i * 256 + t] = outs[(size_t)(r0 + i) * 256 + t];
  __syncthreads();
  int r = t >> 5, c = t & 31;
  if (c < 19) {
    const float* wr = (c < 18) ? (aw + c * 256) : cw;
    float bias = (c < 18) ? ab[c] : cb[0];
    float acc = 0.f;
    for (int k = 0; k < 256; ++k) acc = fmaf(rs[r * 256 + k], wr[k], acc);
    out[(size_t)(r0 + r) * 19 + c] = acc + bias;
  }
}

extern "C" void kernel_launch(void* const* d_in, const int* in_sizes, int n_in,
                              void* d_out, int out_size, void* d_ws, size_t ws_size,
                              hipStream_t stream) {
  (void)in_sizes; (void)n_in; (void)out_size;
  const float* x    = (const float*)d_in[0];
  const float* done = (const float*)d_in[1];
  const float* h0   = (const float*)d_in[2];
  const float* c0   = (const float*)d_in[3];
  const float* w1   = (const float*)d_in[4];
  const float* b1   = (const float*)d_in[5];
  const float* w2   = (const float*)d_in[6];
  const float* b2   = (const float*)d_in[7];
  const float* w3   = (const float*)d_in[8];
  const float* b3   = (const float*)d_in[9];
  const float* fcw  = (const float*)d_in[10];
  const float* fcb  = (const float*)d_in[11];
  const float* wi   = (const float*)d_in[12];
  const float* wh   = (const float*)d_in[13];
  const float* bi   = (const float*)d_in[14];
  const float* bh   = (const float*)d_in[15];
  const float* aw   = (const float*)d_in[16];
  const float* abv  = (const float*)d_in[17];
  const float* cw   = (const float*)d_in[18];
  const float* cbv  = (const float*)d_in[19];
  float* out = (float*)d_out;

  const size_t SZ_A1 = 29491200, SZ_A2 = 9437184, SZ_A3 = 4194304;
  const size_t SZ_F = 2097152, SZ_G = 4194304, SZ_O = 1048576;
  const size_t SZ_SYNC = 131072;       // sync counters + h exchange + packed w
  const size_t need =
      (SZ_A1 + SZ_A2 + SZ_A3 + SZ_F + SZ_G + SZ_O + SZ_SYNC) * 4;
  if (ws_size < need) return;

  float* wsp  = (float*)d_ws;
  float* a1   = wsp;
  float* a2   = a1 + SZ_A1;
  float* a3   = a2 + SZ_A2;
  float* feats= a3 + SZ_A3;
  float* gts  = feats + SZ_F;
  float* outs = gts + SZ_G;
  float* syncb = outs + SZ_O;
  unsigned int* cnt = (unsigned int*)syncb;          // [0, 4096) u32
  unsigned int* h2x = cnt + 4096;                    // [4096, 12288) u32
  float4* wp1 = (float4*)(syncb + 16384);            // 2048 float4 (32 KB)
  float4* wp2 = wp1 + 2048;                          // 8192 float4 (128 KB)

  (void)hipMemsetAsync(cnt, 0, 4096 * sizeof(unsigned int), stream);
  pack_w_kernel<<<40, 256, 0, stream>>>(w1, w2, wp1, wp2);
  conv1_kernel<<<4096, 256, 0, stream>>>(x, wp1, b1, a1);
  conv2_kernel<<<4096, 192, 0, stream>>>(a1, wp2, b2, a2);
  conv3_kernel<<<4096, 256, 0, stream>>>(a2, w3, b3, a3);
  gemm_bias_kernel<<<dim3(8, 64), 256, 0, stream>>>(a3, fcw, fcb, nullptr, feats,
                                                    4096, 512, 1024, 1);
  gemm_bias_kernel<<<dim3(16, 64), 256, 0, stream>>>(feats, wi, bi, bh, gts,
                                                     4096, 1024, 512, 0);
  lstm_pair_kernel<<<64, 512, 0, stream>>>(gts, wh, done, h0, c0, outs, cnt, h2x);
  heads_kernel<<<512, 256, 0, stream>>>(outs, aw, abv, cw, cbv, out);
}

// Round 5
// 1415.774 us; speedup vs baseline: 1.3485x; 1.0203x over previous
//
#include <hip/hip_runtime.h>
#include <math.h>

// ---------------------------------------------------------------------------
// Shapes: T=128, N=32 -> TN=4096
//  x: (4096,4,64,64) f32 | conv1 (32,4,8,8)s4 -> a1 (4096,32,15,15)
//  conv2 (64,32,4,4)s2 -> a2 (4096,64,6,6) | conv3 (64,64,3,3)s1 -> a3 (4096,1024)
//  fc (512,1024) -> feats (4096,512) | lstm wi(1024,512) wh(1024,256) H=256
//  heads: actor(18,256) critic(1,256) -> out (4096,19)
// ---------------------------------------------------------------------------

typedef _Float16 half2_t __attribute__((ext_vector_type(2)));

__device__ __forceinline__ float f4c(float4 v, int k) {
  return k == 0 ? v.x : (k == 1 ? v.y : (k == 2 ? v.z : v.w));
}

// ---- weight pre-pack: lane-major layouts so weight loads coalesce ----------
__global__ __launch_bounds__(256) void pack_w_kernel(
    const float* __restrict__ w1, const float* __restrict__ w2,
    float4* __restrict__ wp1, float4* __restrict__ wp2) {
  const int i = blockIdx.x * 256 + threadIdx.x;
  if (i < 2048) {
    const int og = i & 15, j = i >> 4;
    const int h = j & 3, jj = j >> 2;
    const int ky = jj & 7, c = jj >> 3;
    const float* b0 = w1 + (2 * og) * 256 + c * 64 + ky * 8 + 2 * h;
    const float* b1 = b0 + 256;
    wp1[i] = make_float4(b0[0], b1[0], b0[1], b1[1]);
  } else if (i < 10240) {
    const int i2 = i - 2048;
    const int op = i2 & 31, j = i2 >> 5;
    const int h = j & 1, jj = j >> 1;
    const int ky = jj & 3, c = jj >> 2;
    const float* b0 = w2 + (2 * op) * 512 + c * 16 + ky * 4 + 2 * h;
    const float* b1 = b0 + 512;
    wp2[i2] = make_float4(b0[0], b1[0], b0[1], b1[1]);
  }
}

// ---- conv1 v4: block = frame; packed coalesced weight loads ----
__global__ __launch_bounds__(256) void conv1_kernel(
    const float* __restrict__ x, const float4* __restrict__ wp1,
    const float* __restrict__ bias, float* __restrict__ out) {
  __shared__ float xs[64 * 68];      // 17408 B, one input channel
  const int n = blockIdx.x;
  const int t = threadIdx.x;
  const int oy = t >> 4;             // 0..15 (15 idle in compute)
  const int og = t & 15;
  const int oc0 = og * 2;

  float acc[15][2] = {};
  const float4* xg = (const float4*)(x + (size_t)n * 16384);

  for (int c = 0; c < 4; ++c) {
    __syncthreads();                 // previous channel consumed
    #pragma unroll
    for (int i = 0; i < 4; ++i) {    // stage 1024 float4
      int f4 = i * 256 + t;
      int y = f4 >> 4, xq = f4 & 15;
      *(float4*)&xs[y * 68 + xq * 4] = xg[c * 1024 + f4];
    }
    __syncthreads();
    if (oy < 15) {
      for (int ky = 0; ky < 8; ++ky) {
        const float* xr = &xs[(4 * oy + ky) * 68];
        const float4* wb4 = wp1 + ((c * 8 + ky) * 4) * 16 + og;
        const float4 wv0 = wb4[0];
        const float4 wv1 = wb4[16];
        const float4 wv2 = wb4[32];
        const float4 wv3 = wb4[48];
        const float4 wv[4] = {wv0, wv1, wv2, wv3};
        {
          float4 xv[9];
          #pragma unroll
          for (int i = 0; i < 9; ++i) xv[i] = *(const float4*)(xr + 4 * i);
          #pragma unroll
          for (int h = 0; h < 4; ++h) {
            #pragma unroll
            for (int p = 0; p < 8; ++p) {
              const int k = 4 * p + 2 * h;
              const float xa = f4c(xv[k >> 2], k & 3);
              const float xb = f4c(xv[(k + 1) >> 2], (k + 1) & 3);
              acc[p][0] = fmaf(xa, wv[h].x, fmaf(xb, wv[h].z, acc[p][0]));
              acc[p][1] = fmaf(xa, wv[h].y, fmaf(xb, wv[h].w, acc[p][1]));
            }
          }
        }
        {
          float4 yv[8];
          #pragma unroll
          for (int i = 0; i < 8; ++i) yv[i] = *(const float4*)(xr + 32 + 4 * i);
          #pragma unroll
          for (int h = 0; h < 4; ++h) {
            #pragma unroll
            for (int p = 8; p < 15; ++p) {
              const int q = 4 * p + 2 * h - 32;
              const float xa = f4c(yv[q >> 2], q & 3);
              const float xb = f4c(yv[(q + 1) >> 2], (q + 1) & 3);
              acc[p][0] = fmaf(xa, wv[h].x, fmaf(xb, wv[h].z, acc[p][0]));
              acc[p][1] = fmaf(xa, wv[h].y, fmaf(xb, wv[h].w, acc[p][1]));
            }
          }
        }
      }
    }
  }
  if (oy < 15) {
    const float inv = 1.f / 255.f;
    #pragma unroll
    for (int o = 0; o < 2; ++o) {
      const int oc = oc0 + o;
      const float bb = bias[oc];
      float* orow = out + ((size_t)n * 32 + oc) * 225 + oy * 15;
      #pragma unroll
      for (int p = 0; p < 15; ++p)
        orow[p] = fmaxf(fmaf(acc[p][o], inv, bb), 0.f);
    }
  }
}

// ---- conv2 v4: block = frame (192 thr); packed coalesced weight loads ----
__global__ __launch_bounds__(192) void conv2_kernel(
    const float* __restrict__ a1, const float4* __restrict__ wp2,
    const float* __restrict__ bias, float* __restrict__ out) {
  __shared__ float xs[32 * 15 * 16];   // 30720 B
  const int n = blockIdx.x;
  const int t = threadIdx.x;           // 0..191
  const float* ag = a1 + (size_t)n * 7200;
  for (int i = 0; i < 38; ++i) {
    int idx = i * 192 + t;
    if (idx < 7200) {
      int c = idx / 225, rem = idx - c * 225;
      int row = rem / 15, col = rem - row * 15;
      xs[(c * 15 + row) * 16 + col] = ag[idx];
    }
  }
  __syncthreads();

  const int oy = t >> 5;               // 0..5
  const int op = t & 31;
  const int oc0 = op * 2;
  float acc[6][2] = {};

  for (int c = 0; c < 32; ++c) {
    #pragma unroll
    for (int ky = 0; ky < 4; ++ky) {
      const float* xr = &xs[(c * 15 + 2 * oy + ky) * 16];
      const float4 xa = *(const float4*)(xr);
      const float4 xb = *(const float4*)(xr + 4);
      const float4 xc = *(const float4*)(xr + 8);
      const float2 xd = *(const float2*)(xr + 12);
      const float xv[14] = {xa.x, xa.y, xa.z, xa.w, xb.x, xb.y, xb.z, xb.w,
                            xc.x, xc.y, xc.z, xc.w, xd.x, xd.y};
      const float4 wA = wp2[((c * 4 + ky) * 2 + 0) * 32 + op];
      const float4 wB = wp2[((c * 4 + ky) * 2 + 1) * 32 + op];
      #pragma unroll
      for (int p = 0; p < 6; ++p) {
        const int b = 2 * p;
        acc[p][0] = fmaf(xv[b], wA.x, fmaf(xv[b + 1], wA.z,
                    fmaf(xv[b + 2], wB.x, fmaf(xv[b + 3], wB.z, acc[p][0]))));
        acc[p][1] = fmaf(xv[b], wA.y, fmaf(xv[b + 1], wA.w,
                    fmaf(xv[b + 2], wB.y, fmaf(xv[b + 3], wB.w, acc[p][1]))));
      }
    }
  }
  #pragma unroll
  for (int o = 0; o < 2; ++o) {
    const int oc = oc0 + o;
    const float bb = bias[oc];
    float* orow = out + ((size_t)n * 64 + oc) * 36 + oy * 6;
    #pragma unroll
    for (int p = 0; p < 6; ++p)
      orow[p] = fmaxf(acc[p][o] + bb, 0.f);
  }
}

// ---- conv3 v3: block = frame; x frame AND transposed weights in LDS ----
__global__ __launch_bounds__(256) void conv3_kernel(
    const float* __restrict__ a2, const float* __restrict__ w,
    const float* __restrict__ bias, float* __restrict__ out) {
  __shared__ float wTs[144 * 65];      // 37440 B
  __shared__ float xs2[64 * 36];       // 9216 B
  const int n = blockIdx.x;
  const int t = threadIdx.x;
  const int oy = t >> 6;               // 0..3
  const int oc = t & 63;

  const float* ab = a2 + (size_t)n * 2304;
  #pragma unroll
  for (int i = 0; i < 9; ++i) xs2[i * 256 + t] = ab[i * 256 + t];

  float acc[4] = {};
  for (int c0 = 0; c0 < 64; c0 += 16) {
    __syncthreads();
    #pragma unroll
    for (int i = 0; i < 36; ++i) {
      const int lin = i * 256 + t;
      const int ocs = lin / 144;
      const int rem = lin - ocs * 144;
      wTs[rem * 65 + ocs] = w[(size_t)ocs * 576 + c0 * 9 + rem];
    }
    __syncthreads();
    for (int cc = 0; cc < 16; ++cc) {
      const float* xb = &xs2[(c0 + cc) * 36];
      #pragma unroll
      for (int ky = 0; ky < 3; ++ky) {
        const float* xr = xb + (oy + ky) * 6;
        const float2 x01 = *(const float2*)(xr);
        const float2 x23 = *(const float2*)(xr + 2);
        const float2 x45 = *(const float2*)(xr + 4);
        const float xv[6] = {x01.x, x01.y, x23.x, x23.y, x45.x, x45.y};
        const float* wrow = &wTs[(cc * 9 + ky * 3) * 65 + oc];
        const float wk0 = wrow[0], wk1 = wrow[65], wk2 = wrow[130];
        #pragma unroll
        for (int p = 0; p < 4; ++p)
          acc[p] = fmaf(xv[p], wk0,
                   fmaf(xv[p + 1], wk1,
                   fmaf(xv[p + 2], wk2, acc[p])));
      }
    }
  }
  const float bb = bias[oc];
  float* orow = out + ((size_t)n * 64 + oc) * 16 + oy * 4;
  #pragma unroll
  for (int p = 0; p < 4; ++p)
    orow[p] = fmaxf(acc[p] + bb, 0.f);
}

// ---- generic GEMM: C[M,N] = act(A[M,K] @ B[N,K]^T + bias1 (+bias2)) ----
__global__ __launch_bounds__(256) void gemm_bias_kernel(
    const float* __restrict__ A, const float* __restrict__ B,
    const float* __restrict__ bias1, const float* __restrict__ bias2,
    float* __restrict__ C, int M, int N, int K, int relu) {
  __shared__ float As[16][68];
  __shared__ float Bs[16][68];
  const int t = threadIdx.x;
  const int n0 = blockIdx.x * 64;
  const int m0 = blockIdx.y * 64;
  const int ty = t >> 4, tx = t & 15;
  const int sl = t >> 2, kq = (t & 3) * 4;

  float acc[4][4] = {};

  for (int k0 = 0; k0 < K; k0 += 16) {
    float4 av = *(const float4*)(A + (size_t)(m0 + sl) * K + k0 + kq);
    float4 bv = *(const float4*)(B + (size_t)(n0 + sl) * K + k0 + kq);
    As[kq + 0][sl] = av.x; As[kq + 1][sl] = av.y;
    As[kq + 2][sl] = av.z; As[kq + 3][sl] = av.w;
    Bs[kq + 0][sl] = bv.x; Bs[kq + 1][sl] = bv.y;
    Bs[kq + 2][sl] = bv.z; Bs[kq + 3][sl] = bv.w;
    __syncthreads();
    #pragma unroll
    for (int kk = 0; kk < 16; ++kk) {
      float4 a = *(const float4*)&As[kk][ty * 4];
      float4 b = *(const float4*)&Bs[kk][tx * 4];
      float ar[4] = {a.x, a.y, a.z, a.w};
      float br[4] = {b.x, b.y, b.z, b.w};
      #pragma unroll
      for (int i = 0; i < 4; ++i)
        #pragma unroll
        for (int j = 0; j < 4; ++j)
          acc[i][j] = fmaf(ar[i], br[j], acc[i][j]);
    }
    __syncthreads();
  }

  #pragma unroll
  for (int i = 0; i < 4; ++i) {
    int m = m0 + ty * 4 + i;
    #pragma unroll
    for (int j = 0; j < 4; ++j) {
      int n = n0 + tx * 4 + j;
      float v = acc[i][j] + bias1[n];
      if (bias2) v += bias2[n];
      if (relu) v = fmaxf(v, 0.f);
      C[(size_t)m * N + n] = v;
    }
  }
}

// ---------------------------------------------------------------------------
// LSTM v5b: weight-resident pair-split scan; RMW-only handshake.
//   v4 (passed, 411us): agent fences = buffer_wbl2/buffer_inv, ~2.5us/step of
//   L2-wide writeback+invalidate. v5 (hang suspect): relaxed atomic STORES to
//   publish -- never proven visible across XCD L2s.
//   v5b uses only v4-PROVEN primitives: data published via atomicExch (RMW,
//   executes at the coherence point), wave-local s_waitcnt vmcnt(0) orders
//   data-before-flag, flag bumped via fetch_add (proven), partner polls with
//   relaxed atomic load (proven to observe RMW results), data read back with
//   relaxed atomic loads (same mechanism as the poll). No cache-wide ops.
//   Flags are monotonic per-(env,side) step counters; data parity dbuf
//   prevents overrun (A reaches parity p again only after B's counter shows
//   B consumed p). Spin is bounded so a protocol bug fails with bad absmax
//   instead of hanging the container.
// ---------------------------------------------------------------------------
__global__ __launch_bounds__(512, 2) void lstm_pair_kernel(
    const float* __restrict__ gates_pre, const float* __restrict__ wh,
    const float* __restrict__ done, const float* __restrict__ h0,
    const float* __restrict__ c0, float* __restrict__ outs,
    unsigned int* __restrict__ flags, unsigned int* __restrict__ h2x) {
  __shared__ alignas(16) unsigned int h2s[128];  // masked h (fp16x2), this step
  __shared__ float pLDS[512];                    // full gate sums (incl. pre)
  __shared__ float cLDS[128];                    // cell state, own slice
  __shared__ unsigned short hOut16[128];         // new h as fp16

  const int e = blockIdx.x & 31;     // env
  const int s = blockIdx.x >> 5;     // side (0: j<128, 1: j>=128)
  const int rr = (int)threadIdx.x;   // 0..511
  const int g = rr >> 7;             // gate 0..3
  const int j = rr & 127;
  const int R = g * 256 + s * 128 + j;   // global Wh row owned by this thread

  // ---- one-time: pin this row of Wh in VGPRs as 128 half2 ----
  half2_t w2[128];
  {
    const float4* wr = (const float4*)(wh + (size_t)R * 256);
    #pragma unroll
    for (int i = 0; i < 64; ++i) {
      float4 f = wr[i];
      half2_t a, b;
      a.x = (_Float16)f.x; a.y = (_Float16)f.y;
      b.x = (_Float16)f.z; b.y = (_Float16)f.w;
      w2[2 * i] = a; w2[2 * i + 1] = b;
    }
  }

  // ---- init: full masked h0 (both halves), own c0 slice ----
  if (rr < 128) {
    const float m0 = 1.f - done[e];                 // done[0*32+e]
    float2 h = *(const float2*)(h0 + e * 256 + 2 * rr);
    half2_t hh; hh.x = (_Float16)(h.x * m0); hh.y = (_Float16)(h.y * m0);
    h2s[rr] = __builtin_bit_cast(unsigned int, hh);
    cLDS[rr] = c0[e * 256 + s * 128 + rr];
  }
  __syncthreads();

  const int my_off = s * 64;         // this block's h2-word range in exchange
  const int pa_off = 64 - my_off;    // partner's
  unsigned int* my_cnt = &flags[e * 2 + s];
  unsigned int* pa_cnt = &flags[e * 2 + (1 - s)];

  for (int st = 0; st < 128; ++st) {
    // prefetch (constant inputs; latency hides under the dot phase)
    const float gp = gates_pre[(size_t)(st * 32 + e) * 1024 + R];
    const float d_cur = done[st * 32 + e];
    const float d_nxt = (st < 127) ? done[(st + 1) * 32 + e] : 0.f;

    // ---- dot: full row (K=256) vs broadcast h in LDS, 4 indep chains ----
    float a0 = 0.f, a1 = 0.f, a2 = 0.f, a3 = 0.f;
    #pragma unroll
    for (int i = 0; i < 8; ++i) {
      const uint4 hv0 = *(const uint4*)&h2s[4 * i];
      const uint4 hv1 = *(const uint4*)&h2s[32 + 4 * i];
      const uint4 hv2 = *(const uint4*)&h2s[64 + 4 * i];
      const uint4 hv3 = *(const uint4*)&h2s[96 + 4 * i];
      a0 = __builtin_amdgcn_fdot2(w2[4 * i + 0], __builtin_bit_cast(half2_t, hv0.x), a0, false);
      a1 = __builtin_amdgcn_fdot2(w2[32 + 4 * i + 0], __builtin_bit_cast(half2_t, hv1.x), a1, false);
      a2 = __builtin_amdgcn_fdot2(w2[64 + 4 * i + 0], __builtin_bit_cast(half2_t, hv2.x), a2, false);
      a3 = __builtin_amdgcn_fdot2(w2[96 + 4 * i + 0], __builtin_bit_cast(half2_t, hv3.x), a3, false);
      a0 = __builtin_amdgcn_fdot2(w2[4 * i + 1], __builtin_bit_cast(half2_t, hv0.y), a0, false);
      a1 = __builtin_amdgcn_fdot2(w2[32 + 4 * i + 1], __builtin_bit_cast(half2_t, hv1.y), a1, false);
      a2 = __builtin_amdgcn_fdot2(w2[64 + 4 * i + 1], __builtin_bit_cast(half2_t, hv2.y), a2, false);
      a3 = __builtin_amdgcn_fdot2(w2[96 + 4 * i + 1], __builtin_bit_cast(half2_t, hv3.y), a3, false);
      a0 = __builtin_amdgcn_fdot2(w2[4 * i + 2], __builtin_bit_cast(half2_t, hv0.z), a0, false);
      a1 = __builtin_amdgcn_fdot2(w2[32 + 4 * i + 2], __builtin_bit_cast(half2_t, hv1.z), a1, false);
      a2 = __builtin_amdgcn_fdot2(w2[64 + 4 * i + 2], __builtin_bit_cast(half2_t, hv2.z), a2, false);
      a3 = __builtin_amdgcn_fdot2(w2[96 + 4 * i + 2], __builtin_bit_cast(half2_t, hv3.z), a3, false);
      a0 = __builtin_amdgcn_fdot2(w2[4 * i + 3], __builtin_bit_cast(half2_t, hv0.w), a0, false);
      a1 = __builtin_amdgcn_fdot2(w2[32 + 4 * i + 3], __builtin_bit_cast(half2_t, hv1.w), a1, false);
      a2 = __builtin_amdgcn_fdot2(w2[64 + 4 * i + 3], __builtin_bit_cast(half2_t, hv2.w), a2, false);
      a3 = __builtin_amdgcn_fdot2(w2[96 + 4 * i + 3], __builtin_bit_cast(half2_t, hv3.w), a3, false);
    }
    pLDS[rr] = a0 + a1 + a2 + a3 + gp;
    __syncthreads();

    // ---- cell update (own slice only; gates are complete sums) ----
    if (rr < 128) {
      const float m = 1.f - d_cur;
      float c = cLDS[rr] * m;
      float iv = pLDS[rr];
      float fv = pLDS[128 + rr];
      float gv = pLDS[256 + rr];
      float ov = pLDS[384 + rr];
      float ig = 1.f / (1.f + expf(-iv));
      float fg = 1.f / (1.f + expf(-fv));
      float og = 1.f / (1.f + expf(-ov));
      float cn = fmaf(fg, c, ig * tanhf(gv));
      float hn = og * tanhf(cn);
      cLDS[rr] = cn;
      outs[(size_t)st * 8192 + e * 256 + s * 128 + rr] = hn;
      hOut16[rr] = __builtin_bit_cast(unsigned short, (_Float16)hn);
    }
    __syncthreads();

    // ---- pairwise h exchange (skip after last step) ----
    if (st < 127) {
      unsigned int* hx = h2x + (st & 1) * 4096 + e * 128;  // parity dbuf
      if (rr < 64) {                 // exactly wave 0
        unsigned int w = (unsigned int)hOut16[2 * rr] |
                         ((unsigned int)hOut16[2 * rr + 1] << 16);
        atomicExch(&hx[my_off + rr], w);                // RMW publish
        h2s[my_off + rr] = (d_nxt != 0.f) ? 0u : w;     // own half, masked
        // all 64 data RMWs acked at the coherence point...
        asm volatile("s_waitcnt vmcnt(0)" ::: "memory");
        if (rr == 0)                                    // ...then bump counter
          __hip_atomic_fetch_add(my_cnt, 1u, __ATOMIC_RELAXED,
                                 __HIP_MEMORY_SCOPE_AGENT);
      }
      if (rr == 0) {
        int spins = 0;
        while (__hip_atomic_load(pa_cnt, __ATOMIC_RELAXED,
                                 __HIP_MEMORY_SCOPE_AGENT) < (unsigned int)(st + 1)
               && spins < (1 << 20)) {
          __builtin_amdgcn_s_sleep(1);
          ++spins;
        }
      }
      __syncthreads();
      if (rr < 64) {
        unsigned int w = __hip_atomic_load(&hx[pa_off + rr], __ATOMIC_RELAXED,
                                           __HIP_MEMORY_SCOPE_AGENT);
        h2s[pa_off + rr] = (d_nxt != 0.f) ? 0u : w;
      }
      __syncthreads();
    }
  }
}

// ---- heads ----
__global__ __launch_bounds__(256) void heads_kernel(
    const float* __restrict__ outs, const float* __restrict__ aw,
    const float* __restrict__ ab, const float* __restrict__ cw,
    const float* __restrict__ cb, float* __restrict__ out) {
  __shared__ float rs[8 * 256];
  const int t = threadIdx.x;
  const int r0 = blockIdx.x * 8;
  for (int i = 0; i < 8; ++i)
    rs[i * 256 + t] = outs[(size_t)(r0 + i) * 256 + t];
  __syncthreads();
  int r = t >> 5, c = t & 31;
  if (c < 19) {
    const float* wr = (c < 18) ? (aw + c * 256) : cw;
    float bias = (c < 18) ? ab[c] : cb[0];
    float acc = 0.f;
    for (int k = 0; k < 256; ++k) acc = fmaf(rs[r * 256 + k], wr[k], acc);
    out[(size_t)(r0 + r) * 19 + c] = acc + bias;
  }
}

extern "C" void kernel_launch(void* const* d_in, const int* in_sizes, int n_in,
                              void* d_out, int out_size, void* d_ws, size_t ws_size,
                              hipStream_t stream) {
  (void)in_sizes; (void)n_in; (void)out_size;
  const float* x    = (const float*)d_in[0];
  const float* done = (const float*)d_in[1];
  const float* h0   = (const float*)d_in[2];
  const float* c0   = (const float*)d_in[3];
  const float* w1   = (const float*)d_in[4];
  const float* b1   = (const float*)d_in[5];
  const float* w2   = (const float*)d_in[6];
  const float* b2   = (const float*)d_in[7];
  const float* w3   = (const float*)d_in[8];
  const float* b3   = (const float*)d_in[9];
  const float* fcw  = (const float*)d_in[10];
  const float* fcb  = (const float*)d_in[11];
  const float* wi   = (const float*)d_in[12];
  const float* wh   = (const float*)d_in[13];
  const float* bi   = (const float*)d_in[14];
  const float* bh   = (const float*)d_in[15];
  const float* aw   = (const float*)d_in[16];
  const float* abv  = (const float*)d_in[17];
  const float* cw   = (const float*)d_in[18];
  const float* cbv  = (const float*)d_in[19];
  float* out = (float*)d_out;

  const size_t SZ_A1 = 29491200, SZ_A2 = 9437184, SZ_A3 = 4194304;
  const size_t SZ_F = 2097152, SZ_G = 4194304, SZ_O = 1048576;
  const size_t SZ_SYNC = 131072;       // flags + h exchange + packed w
  const size_t need =
      (SZ_A1 + SZ_A2 + SZ_A3 + SZ_F + SZ_G + SZ_O + SZ_SYNC) * 4;
  if (ws_size < need) return;

  float* wsp  = (float*)d_ws;
  float* a1   = wsp;
  float* a2   = a1 + SZ_A1;
  float* a3   = a2 + SZ_A2;
  float* feats= a3 + SZ_A3;
  float* gts  = feats + SZ_F;
  float* outs = gts + SZ_G;
  float* syncb = outs + SZ_O;
  unsigned int* flags = (unsigned int*)syncb;        // [0, 64) u32 used
  unsigned int* h2x = flags + 4096;                  // [4096, 12288) u32
  float4* wp1 = (float4*)(syncb + 16384);            // 2048 float4 (32 KB)
  float4* wp2 = wp1 + 2048;                          // 8192 float4 (128 KB)

  (void)hipMemsetAsync(flags, 0, 4096 * sizeof(unsigned int), stream);
  pack_w_kernel<<<40, 256, 0, stream>>>(w1, w2, wp1, wp2);
  conv1_kernel<<<4096, 256, 0, stream>>>(x, wp1, b1, a1);
  conv2_kernel<<<4096, 192, 0, stream>>>(a1, wp2, b2, a2);
  conv3_kernel<<<4096, 256, 0, stream>>>(a2, w3, b3, a3);
  gemm_bias_kernel<<<dim3(8, 64), 256, 0, stream>>>(a3, fcw, fcb, nullptr, feats,
                                                    4096, 512, 1024, 1);
  gemm_bias_kernel<<<dim3(16, 64), 256, 0, stream>>>(feats, wi, bi, bh, gts,
                                                     4096, 1024, 512, 0);
  lstm_pair_kernel<<<64, 512, 0, stream>>>(gts, wh, done, h0, c0, outs, flags, h2x);
  heads_kernel<<<512, 256, 0, stream>>>(outs, aw, abv, cw, cbv, out);
}